// Round 8
// baseline (367.961 us; speedup 1.0000x reference)
//
#include <hip/hip_runtime.h>

constexpr int NN = 100000;   // nodes
constexpr int DI = 256;      // in features
constexpr int DO = 128;      // out features
constexpr int NE = 1600000;  // edges

constexpr int TILE = 2048;                        // edges per partition block
constexpr int RCAP = 64;                          // per-row slots (deg~Pois(16); P(>64)~1e-13)

constexpr int NGB = (NN + 63) / 64;               // 1563 gemm blocks
constexpr int NPB = (NE + TILE - 1) / TILE;       // 782 part blocks

typedef __bf16 bf16x8 __attribute__((ext_vector_type(8)));
typedef float  f32x4  __attribute__((ext_vector_type(4)));

__device__ inline unsigned short f2bf(float f) {
    union { float f; unsigned u; } v; v.f = f;
    return (unsigned short)((v.u + 0x7FFF + ((v.u >> 16) & 1)) >> 16);
}
__device__ inline float bf2f(unsigned u16) {
    union { unsigned u; float f; } v; v.u = u16 << 16;
    return v.f;
}

// ---------------- W transpose: W[256][128] f32 -> Wt[128][256] bf16 ----------
__global__ __launch_bounds__(256)
void wt_kernel(const float* __restrict__ W, unsigned short* __restrict__ Wt) {
    __shared__ float t[32][33];
    const int tx = threadIdx.x & 31, ty = threadIdx.x >> 5;
    const int k0 = (blockIdx.x >> 2) * 32, n0 = (blockIdx.x & 3) * 32;
#pragma unroll
    for (int i = 0; i < 32; i += 8)
        t[ty + i][tx] = W[(size_t)(k0 + ty + i) * DO + n0 + tx];
    __syncthreads();
#pragma unroll
    for (int i = 0; i < 32; i += 8)
        Wt[(size_t)(n0 + ty + i) * DI + k0 + tx] = f2bf(t[tx][ty + i]);
}

// ---------------- fused GEMM + partition (interleaved block fusion) ---------
// R7 post-mortem: fusion works (total -30us). But part's LDS histogram
// pushed bank conflicts 1.8M->11.6M, and bgather still burns a full LDS
// counting sort before gathering. R8: part scatters each edge DIRECTLY to
// its row's list (global per-row cursor atomicAdd; deg~Pois(16), RCAP=64,
// guarded). Part body loses all LDS; bgather loses the entire sort.
// Block mapping interleaves part among early gemm blocks (bijective):
//   bid<1564: odd -> part(bid>>1), even -> gemm(bid>>1)
//   bid>=1564: gemm(bid-782)
__global__ __launch_bounds__(256)
void gemm_part_kernel(const float* __restrict__ x, const float* __restrict__ mask,
                      const unsigned short* __restrict__ Wt,
                      unsigned short* __restrict__ h,
                      const int* __restrict__ erow, const int* __restrict__ ecol,
                      const float* __restrict__ ew, int* __restrict__ rcnt,
                      int2* __restrict__ ecsr) {
    __shared__ unsigned short As[64][72];
    __shared__ unsigned short Bs[128][72];

    const int bid = blockIdx.x;
    const bool is_part = (bid < 2 * NPB) && (bid & 1);

    if (!is_part) {
        // ---------------- gemm body (proven 92 us baseline, verbatim) ------
        const int gb   = (bid < 2 * NPB) ? (bid >> 1) : (bid - NPB);
        const int tid  = threadIdx.x;
        const int lane = tid & 63;
        const int w    = tid >> 6;          // wave 0..3
        const int m0   = gb * 64;
        const int mw   = w * 16;            // wave's 16-row slice
        const int l15  = lane & 15;
        const int l4   = lane >> 4;

        f32x4 acc[8];
#pragma unroll
        for (int ct = 0; ct < 8; ++ct) acc[ct] = (f32x4){0.f, 0.f, 0.f, 0.f};

        const int lr = tid >> 4;         // 0..15: row within 16-row group
        const int lk = (tid & 15) * 4;   // 0..60: k offset (float4)

        float4 xv[4], mv[4];
        const float4 z4 = make_float4(0.f, 0.f, 0.f, 0.f);

        // prefetch kc = 0
#pragma unroll
        for (int p = 0; p < 4; ++p) {
            const int r = m0 + p * 16 + lr;
            if (r < NN) {
                xv[p] = *(const float4*)(x    + (size_t)r * DI + lk);
                mv[p] = *(const float4*)(mask + (size_t)r * DI + lk);
            } else { xv[p] = z4; mv[p] = z4; }
        }

        for (int kc = 0; kc < DI; kc += 64) {
            __syncthreads();   // prev MFMA done reading LDS
            // store prefetched A (convert to bf16)
#pragma unroll
            for (int p = 0; p < 4; ++p) {
                ushort4 pk;
                pk.x = f2bf(xv[p].x * mv[p].x); pk.y = f2bf(xv[p].y * mv[p].y);
                pk.z = f2bf(xv[p].z * mv[p].z); pk.w = f2bf(xv[p].w * mv[p].w);
                *(ushort4*)&As[p * 16 + lr][lk] = pk;
            }
            // stage B (L2-hot, 16 KB)
            {
                const int kl = (tid & 7) * 8;
#pragma unroll
                for (int p = 0; p < 4; ++p) {
                    const int n = p * 32 + (tid >> 3);
                    *(uint4*)&Bs[n][kl] =
                        *(const uint4*)(Wt + (size_t)n * DI + kc + kl);
                }
            }
            // prefetch next K-tile (overlaps with MFMA below)
            if (kc + 64 < DI) {
#pragma unroll
                for (int p = 0; p < 4; ++p) {
                    const int r = m0 + p * 16 + lr;
                    if (r < NN) {
                        xv[p] = *(const float4*)(x    + (size_t)r * DI + kc + 64 + lk);
                        mv[p] = *(const float4*)(mask + (size_t)r * DI + kc + 64 + lk);
                    } else { xv[p] = z4; mv[p] = z4; }
                }
            }
            __syncthreads();
#pragma unroll
            for (int ks = 0; ks < 2; ++ks) {
                const int ko = ks * 32 + l4 * 8;
                const bf16x8 a0 = *(const bf16x8*)&As[mw + l15][ko];
#pragma unroll
                for (int ct = 0; ct < 8; ++ct) {
                    const bf16x8 b = *(const bf16x8*)&Bs[ct * 16 + l15][ko];
                    acc[ct] = __builtin_amdgcn_mfma_f32_16x16x32_bf16(a0, b, acc[ct], 0, 0, 0);
                }
            }
        }
        // epilogue: D[row = l4*4+reg][col = l15]
#pragma unroll
        for (int ct = 0; ct < 8; ++ct)
#pragma unroll
            for (int reg = 0; reg < 4; ++reg) {
                const int row = m0 + mw + l4 * 4 + reg;
                if (row < NN)
                    h[(size_t)row * DO + ct * 16 + l15] = f2bf(acc[ct][reg]);
            }
    } else {
        // ---------------- partition body: direct per-row scatter, no LDS ---
        const int t  = threadIdx.x;
        const int e0 = (bid >> 1) * TILE;
#pragma unroll 4
        for (int k = 0; k < TILE; k += 256) {
            const int e = e0 + k + t;
            if (e < NE) {
                const int row = erow[e];
                const int pos = atomicAdd(&rcnt[row], 1);
                if (pos < RCAP) {
                    int2 v;
                    v.x = ecol[e];
                    v.y = __float_as_int(ew[e]);
                    ecsr[(size_t)row * RCAP + pos] = v;
                }
            }
        }
    }
}

// ---------------- row gather: contiguous per-row edge lists, no sort --------
// 16-lane group per row; edge int2 broadcast-read (all 16 lanes same addr),
// h row read 16B/lane (256B contiguous per edge). LDS = 0.
__global__ __launch_bounds__(256)
void bgather_kernel(const unsigned short* __restrict__ h,
                    const int* __restrict__ rcnt,
                    const int2* __restrict__ ecsr, float* __restrict__ out) {
    const int t   = threadIdx.x;
    const int l16 = t & 15, g = t >> 4;            // 16 groups per block
    const int gid0 = blockIdx.x * 16 + g;
    const int ngrp = gridDim.x * 16;

    for (int r = gid0; r < NN; r += ngrp) {
        int deg = rcnt[r];
        if (deg > RCAP) deg = RCAP;
        const int2* ep = ecsr + (size_t)r * RCAP;

        float acc[8];
#pragma unroll
        for (int i = 0; i < 8; ++i) acc[i] = 0.f;

        int j = 0;
        for (; j + 2 <= deg; j += 2) {
            const int2 e0 = ep[j], e1 = ep[j + 1];
            const float w0 = __int_as_float(e0.y);
            const float w1 = __int_as_float(e1.y);
            const uint4 q0 = *(const uint4*)(h + (size_t)e0.x * DO + l16 * 8);
            const uint4 q1 = *(const uint4*)(h + (size_t)e1.x * DO + l16 * 8);
            const unsigned* u0 = (const unsigned*)&q0;
            const unsigned* u1 = (const unsigned*)&q1;
#pragma unroll
            for (int i = 0; i < 4; ++i) {
                acc[2 * i + 0] += w0 * bf2f(u0[i] & 0xFFFF) + w1 * bf2f(u1[i] & 0xFFFF);
                acc[2 * i + 1] += w0 * bf2f(u0[i] >> 16)    + w1 * bf2f(u1[i] >> 16);
            }
        }
        if (j < deg) {
            const int2 e0 = ep[j];
            const float w0 = __int_as_float(e0.y);
            const uint4 q0 = *(const uint4*)(h + (size_t)e0.x * DO + l16 * 8);
            const unsigned* u0 = (const unsigned*)&q0;
#pragma unroll
            for (int i = 0; i < 4; ++i) {
                acc[2 * i + 0] += w0 * bf2f(u0[i] & 0xFFFF);
                acc[2 * i + 1] += w0 * bf2f(u0[i] >> 16);
            }
        }
        float* op = out + (size_t)r * DO + l16 * 8;
        *(float4*)(op + 0) = make_float4(fmaxf(acc[0], 0.f), fmaxf(acc[1], 0.f),
                                         fmaxf(acc[2], 0.f), fmaxf(acc[3], 0.f));
        *(float4*)(op + 4) = make_float4(fmaxf(acc[4], 0.f), fmaxf(acc[5], 0.f),
                                         fmaxf(acc[6], 0.f), fmaxf(acc[7], 0.f));
    }
}

extern "C" void kernel_launch(void* const* d_in, const int* in_sizes, int n_in,
                              void* d_out, int out_size, void* d_ws, size_t ws_size,
                              hipStream_t stream) {
    const float* x    = (const float*)d_in[0];
    const float* mask = (const float*)d_in[1];
    const float* W    = (const float*)d_in[2];
    const int*   erow = (const int*)d_in[3];
    const int*   ecol = (const int*)d_in[4];
    const float* ew   = (const float*)d_in[5];
    float* out = (float*)d_out;

    char* p = (char*)d_ws;
    unsigned short* h  = (unsigned short*)p;  p += (size_t)NN * DO * 2;   // 25.6 MB
    unsigned short* Wt = (unsigned short*)p;  p += (size_t)DO * DI * 2;   // 64 KB
    int* rcnt = (int*)p;                      p += (size_t)NN * 4;        // 400 KB
    int2* ecsr = (int2*)p;                    // NN*RCAP*8 = 51.2 MB

    hipMemsetAsync(rcnt, 0, (size_t)NN * sizeof(int), stream);

    wt_kernel<<<32, 256, 0, stream>>>(W, Wt);
    gemm_part_kernel<<<NGB + NPB, 256, 0, stream>>>(x, mask, Wt, h,
                                                    erow, ecol, ew, rcnt, ecsr);
    bgather_kernel<<<1563, 256, 0, stream>>>(h, rcnt, ecsr, out);
}

// Round 9
// 367.695 us; speedup vs baseline: 1.0007x; 1.0007x over previous
//
#include <hip/hip_runtime.h>

constexpr int NN = 100000;   // nodes
constexpr int DI = 256;      // in features
constexpr int DO = 128;      // out features
constexpr int NE = 1600000;  // edges

constexpr int TILE = 2048;                        // edges per partition block
constexpr int RCAP = 64;                          // per-row slots (deg~Pois(16); P(>64)~1e-13)

constexpr int NGB = (NN + 63) / 64;               // 1563 gemm blocks
constexpr int NPB = (NE + TILE - 1) / TILE;       // 782 part blocks

typedef __bf16 bf16x8 __attribute__((ext_vector_type(8)));
typedef float  f32x4  __attribute__((ext_vector_type(4)));

__device__ inline unsigned short f2bf(float f) {
    union { float f; unsigned u; } v; v.f = f;
    return (unsigned short)((v.u + 0x7FFF + ((v.u >> 16) & 1)) >> 16);
}
__device__ inline float bf2f(unsigned u16) {
    union { unsigned u; float f; } v; v.u = u16 << 16;
    return v.f;
}

// ---------------- W transpose: W[256][128] f32 -> Wt[128][256] bf16 ----------
__global__ __launch_bounds__(256)
void wt_kernel(const float* __restrict__ W, unsigned short* __restrict__ Wt) {
    __shared__ float t[32][33];
    const int tx = threadIdx.x & 31, ty = threadIdx.x >> 5;
    const int k0 = (blockIdx.x >> 2) * 32, n0 = (blockIdx.x & 3) * 32;
#pragma unroll
    for (int i = 0; i < 32; i += 8)
        t[ty + i][tx] = W[(size_t)(k0 + ty + i) * DO + n0 + tx];
    __syncthreads();
#pragma unroll
    for (int i = 0; i < 32; i += 8)
        Wt[(size_t)(n0 + ty + i) * DI + k0 + tx] = f2bf(t[tx][ty + i]);
}

// ---------------- fused GEMM + partition (interleaved block fusion) ---------
// R8: kept verbatim. Part scatters edges directly to per-row lists (global
// cursor atomicAdd). WRITE inflation from scattered 8B stores costs ~8us vs
// R7's bucketed variant, but buys the sort-free bgather.
__global__ __launch_bounds__(256)
void gemm_part_kernel(const float* __restrict__ x, const float* __restrict__ mask,
                      const unsigned short* __restrict__ Wt,
                      unsigned short* __restrict__ h,
                      const int* __restrict__ erow, const int* __restrict__ ecol,
                      const float* __restrict__ ew, int* __restrict__ rcnt,
                      int2* __restrict__ ecsr) {
    __shared__ unsigned short As[64][72];
    __shared__ unsigned short Bs[128][72];

    const int bid = blockIdx.x;
    const bool is_part = (bid < 2 * NPB) && (bid & 1);

    if (!is_part) {
        // ---------------- gemm body (proven 92 us baseline, verbatim) ------
        const int gb   = (bid < 2 * NPB) ? (bid >> 1) : (bid - NPB);
        const int tid  = threadIdx.x;
        const int lane = tid & 63;
        const int w    = tid >> 6;          // wave 0..3
        const int m0   = gb * 64;
        const int mw   = w * 16;            // wave's 16-row slice
        const int l15  = lane & 15;
        const int l4   = lane >> 4;

        f32x4 acc[8];
#pragma unroll
        for (int ct = 0; ct < 8; ++ct) acc[ct] = (f32x4){0.f, 0.f, 0.f, 0.f};

        const int lr = tid >> 4;         // 0..15: row within 16-row group
        const int lk = (tid & 15) * 4;   // 0..60: k offset (float4)

        float4 xv[4], mv[4];
        const float4 z4 = make_float4(0.f, 0.f, 0.f, 0.f);

        // prefetch kc = 0
#pragma unroll
        for (int p = 0; p < 4; ++p) {
            const int r = m0 + p * 16 + lr;
            if (r < NN) {
                xv[p] = *(const float4*)(x    + (size_t)r * DI + lk);
                mv[p] = *(const float4*)(mask + (size_t)r * DI + lk);
            } else { xv[p] = z4; mv[p] = z4; }
        }

        for (int kc = 0; kc < DI; kc += 64) {
            __syncthreads();   // prev MFMA done reading LDS
            // store prefetched A (convert to bf16)
#pragma unroll
            for (int p = 0; p < 4; ++p) {
                ushort4 pk;
                pk.x = f2bf(xv[p].x * mv[p].x); pk.y = f2bf(xv[p].y * mv[p].y);
                pk.z = f2bf(xv[p].z * mv[p].z); pk.w = f2bf(xv[p].w * mv[p].w);
                *(ushort4*)&As[p * 16 + lr][lk] = pk;
            }
            // stage B (L2-hot, 16 KB)
            {
                const int kl = (tid & 7) * 8;
#pragma unroll
                for (int p = 0; p < 4; ++p) {
                    const int n = p * 32 + (tid >> 3);
                    *(uint4*)&Bs[n][kl] =
                        *(const uint4*)(Wt + (size_t)n * DI + kc + kl);
                }
            }
            // prefetch next K-tile (overlaps with MFMA below)
            if (kc + 64 < DI) {
#pragma unroll
                for (int p = 0; p < 4; ++p) {
                    const int r = m0 + p * 16 + lr;
                    if (r < NN) {
                        xv[p] = *(const float4*)(x    + (size_t)r * DI + kc + 64 + lk);
                        mv[p] = *(const float4*)(mask + (size_t)r * DI + kc + 64 + lk);
                    } else { xv[p] = z4; mv[p] = z4; }
                }
            }
            __syncthreads();
#pragma unroll
            for (int ks = 0; ks < 2; ++ks) {
                const int ko = ks * 32 + l4 * 8;
                const bf16x8 a0 = *(const bf16x8*)&As[mw + l15][ko];
#pragma unroll
                for (int ct = 0; ct < 8; ++ct) {
                    const bf16x8 b = *(const bf16x8*)&Bs[ct * 16 + l15][ko];
                    acc[ct] = __builtin_amdgcn_mfma_f32_16x16x32_bf16(a0, b, acc[ct], 0, 0, 0);
                }
            }
        }
        // epilogue: D[row = l4*4+reg][col = l15]
#pragma unroll
        for (int ct = 0; ct < 8; ++ct)
#pragma unroll
            for (int reg = 0; reg < 4; ++reg) {
                const int row = m0 + mw + l4 * 4 + reg;
                if (row < NN)
                    h[(size_t)row * DO + ct * 16 + l15] = f2bf(acc[ct][reg]);
            }
    } else {
        // ---------------- partition body: direct per-row scatter, no LDS ---
        const int t  = threadIdx.x;
        const int e0 = (bid >> 1) * TILE;
#pragma unroll 4
        for (int k = 0; k < TILE; k += 256) {
            const int e = e0 + k + t;
            if (e < NE) {
                const int row = erow[e];
                const int pos = atomicAdd(&rcnt[row], 1);
                if (pos < RCAP) {
                    int2 v;
                    v.x = ecol[e];
                    v.y = __float_as_int(ew[e]);
                    ecsr[(size_t)row * RCAP + pos] = v;
                }
            }
        }
    }
}

// ---------------- row gather: 8-deep pipelined random gather ----------------
// R8 post-mortem: sort removal changed bgather by ~0us -> it is ~100%
// random-gather latency-bound (2-deep chain, ~2 gathers in flight/group),
// at 228us vs a ~40-80us L3-BW floor. R9: per 8-edge chunk, read 4 uint4
// descriptor words (broadcast), issue 8 INDEPENDENT 256B h gathers into
// named registers, then accumulate. 4x the memory parallelism per group.
__device__ inline void acc8(float* acc, const uint4& q, float w) {
    const unsigned* u = (const unsigned*)&q;
#pragma unroll
    for (int i = 0; i < 4; ++i) {
        acc[2 * i + 0] += w * bf2f(u[i] & 0xFFFF);
        acc[2 * i + 1] += w * bf2f(u[i] >> 16);
    }
}

__global__ __launch_bounds__(256)
void bgather_kernel(const unsigned short* __restrict__ h,
                    const int* __restrict__ rcnt,
                    const int2* __restrict__ ecsr, float* __restrict__ out) {
    const int t   = threadIdx.x;
    const int l16 = t & 15, g = t >> 4;            // 16 groups per block
    const int gid0 = blockIdx.x * 16 + g;
    const int ngrp = gridDim.x * 16;
    const int ho   = l16 * 8;

    for (int r = gid0; r < NN; r += ngrp) {
        int deg = rcnt[r];
        if (deg > RCAP) deg = RCAP;
        const int2* ep = ecsr + (size_t)r * RCAP;

        float acc[8];
#pragma unroll
        for (int i = 0; i < 8; ++i) acc[i] = 0.f;

        int j = 0;
        for (; j + 8 <= deg; j += 8) {
            const uint4 d0 = *(const uint4*)(ep + j);
            const uint4 d1 = *(const uint4*)(ep + j + 2);
            const uint4 d2 = *(const uint4*)(ep + j + 4);
            const uint4 d3 = *(const uint4*)(ep + j + 6);
            const uint4 q0 = *(const uint4*)(h + (size_t)d0.x * DO + ho);
            const uint4 q1 = *(const uint4*)(h + (size_t)d0.z * DO + ho);
            const uint4 q2 = *(const uint4*)(h + (size_t)d1.x * DO + ho);
            const uint4 q3 = *(const uint4*)(h + (size_t)d1.z * DO + ho);
            const uint4 q4 = *(const uint4*)(h + (size_t)d2.x * DO + ho);
            const uint4 q5 = *(const uint4*)(h + (size_t)d2.z * DO + ho);
            const uint4 q6 = *(const uint4*)(h + (size_t)d3.x * DO + ho);
            const uint4 q7 = *(const uint4*)(h + (size_t)d3.z * DO + ho);
            acc8(acc, q0, __int_as_float(d0.y));
            acc8(acc, q1, __int_as_float(d0.w));
            acc8(acc, q2, __int_as_float(d1.y));
            acc8(acc, q3, __int_as_float(d1.w));
            acc8(acc, q4, __int_as_float(d2.y));
            acc8(acc, q5, __int_as_float(d2.w));
            acc8(acc, q6, __int_as_float(d3.y));
            acc8(acc, q7, __int_as_float(d3.w));
        }
        for (; j + 2 <= deg; j += 2) {
            const int2 e0 = ep[j], e1 = ep[j + 1];
            const uint4 q0 = *(const uint4*)(h + (size_t)e0.x * DO + ho);
            const uint4 q1 = *(const uint4*)(h + (size_t)e1.x * DO + ho);
            acc8(acc, q0, __int_as_float(e0.y));
            acc8(acc, q1, __int_as_float(e1.y));
        }
        if (j < deg) {
            const int2 e0 = ep[j];
            const uint4 q0 = *(const uint4*)(h + (size_t)e0.x * DO + ho);
            acc8(acc, q0, __int_as_float(e0.y));
        }
        float* op = out + (size_t)r * DO + ho;
        *(float4*)(op + 0) = make_float4(fmaxf(acc[0], 0.f), fmaxf(acc[1], 0.f),
                                         fmaxf(acc[2], 0.f), fmaxf(acc[3], 0.f));
        *(float4*)(op + 4) = make_float4(fmaxf(acc[4], 0.f), fmaxf(acc[5], 0.f),
                                         fmaxf(acc[6], 0.f), fmaxf(acc[7], 0.f));
    }
}

extern "C" void kernel_launch(void* const* d_in, const int* in_sizes, int n_in,
                              void* d_out, int out_size, void* d_ws, size_t ws_size,
                              hipStream_t stream) {
    const float* x    = (const float*)d_in[0];
    const float* mask = (const float*)d_in[1];
    const float* W    = (const float*)d_in[2];
    const int*   erow = (const int*)d_in[3];
    const int*   ecol = (const int*)d_in[4];
    const float* ew   = (const float*)d_in[5];
    float* out = (float*)d_out;

    char* p = (char*)d_ws;
    unsigned short* h  = (unsigned short*)p;  p += (size_t)NN * DO * 2;   // 25.6 MB
    unsigned short* Wt = (unsigned short*)p;  p += (size_t)DO * DI * 2;   // 64 KB
    int* rcnt = (int*)p;                      p += (size_t)NN * 4;        // 400 KB
    int2* ecsr = (int2*)p;                    // NN*RCAP*8 = 51.2 MB

    hipMemsetAsync(rcnt, 0, (size_t)NN * sizeof(int), stream);

    wt_kernel<<<32, 256, 0, stream>>>(W, Wt);
    gemm_part_kernel<<<NGB + NPB, 256, 0, stream>>>(x, mask, Wt, h,
                                                    erow, ecol, ew, rcnt, ecsr);
    bgather_kernel<<<2048, 256, 0, stream>>>(h, rcnt, ecsr, out);
}